// Round 6
// baseline (317.095 us; speedup 1.0000x reference)
//
#include <hip/hip_runtime.h>
#include <hip/hip_bf16.h>

using short8  = __attribute__((ext_vector_type(8))) short;
using short4v = __attribute__((ext_vector_type(4))) short;
using f32x4   = __attribute__((ext_vector_type(4))) float;

#if __has_builtin(__builtin_amdgcn_exp2f)
#define EXP2(x) __builtin_amdgcn_exp2f(x)
#else
#define EXP2(x) __expf(0.6931471805599453f*(x))
#endif

__device__ __forceinline__ unsigned short f2bf(float x){
  union { float f; unsigned u; } c; c.f = x;
  unsigned u = c.u + 0x7FFFu + ((c.u >> 16) & 1u);
  return (unsigned short)(u >> 16);
}

__device__ __forceinline__ unsigned pack_bf16_rn(float a, float b){
  __hip_bfloat162 t = __float22bfloat162_rn(make_float2(a, b));
  unsigned u; __builtin_memcpy(&u, &t, 4);
  return u;
}

// ---------------- fused prep: all dtype conversions in one launch ----------------
__global__ __launch_bounds__(256) void prep(const float* __restrict__ X, const int* __restrict__ Mk,
                                            const float* __restrict__ Wq, const float* __restrict__ Wk,
                                            const float* __restrict__ Wv, const float* __restrict__ Wo,
                                            unsigned short* __restrict__ Xb, unsigned short* __restrict__ Wqkv,
                                            unsigned short* __restrict__ Wob, unsigned char* __restrict__ M8)
{
  const int bid = blockIdx.x, tid = threadIdx.x;
  if (bid < 8192){
    const float* src; unsigned short* dst; float scale; int i;
    if (bid < 4096)      { src = X;  dst = Xb;             scale = 1.0f;          i = bid*1024 + tid*4; }
    else if (bid < 5120) { src = Wq; dst = Wqkv;           scale = 0.18033688f;   i = (bid-4096)*1024 + tid*4; } // 1/8 * log2(e)
    else if (bid < 6144) { src = Wk; dst = Wqkv + 1048576; scale = 1.0f;          i = (bid-5120)*1024 + tid*4; }
    else if (bid < 7168) { src = Wv; dst = Wqkv + 2097152; scale = 1.0f;          i = (bid-6144)*1024 + tid*4; }
    else                 { src = Wo; dst = Wob;            scale = 1.0f;          i = (bid-7168)*1024 + tid*4; }
    float4 v = *(const float4*)(src + i);
    ushort4 o;
    o.x = f2bf(v.x * scale); o.y = f2bf(v.y * scale);
    o.z = f2bf(v.z * scale); o.w = f2bf(v.w * scale);
    *(ushort4*)(dst + i) = o;
  } else {
    int i = (bid - 8192)*1024 + tid*4;
    int4 v = *(const int4*)(Mk + i);
    unsigned out = (v.x ? 1u : 0u) | ((v.y ? 1u : 0u) << 8) |
                   ((v.z ? 1u : 0u) << 16) | ((v.w ? 1u : 0u) << 24);
    *(unsigned*)(M8 + i) = out;
  }
}

// ---------------- async global->LDS, width 16 ----------------
__device__ __forceinline__ void stage16(const unsigned short* g, unsigned short* l){
  __builtin_amdgcn_global_load_lds(
      (const __attribute__((address_space(1))) void*)g,
      (__attribute__((address_space(3))) void*)l, 16, 0, 0);
}

// ---------------- gemm1: QKV = Xb * Wqkv^T; V-blocks write Vg transposed ----------
__global__ __launch_bounds__(256) void gemm_qkv(const unsigned short* __restrict__ A,
                                                const unsigned short* __restrict__ B,
                                                unsigned short* __restrict__ C,
                                                unsigned short* __restrict__ Vg)
{
  __shared__ unsigned short As[128*32];
  __shared__ unsigned short Bs[128*32];
  const int tid = threadIdx.x;
  const int wave = tid >> 6, lane = tid & 63, l16 = lane & 15, quad = lane >> 4;
  const int bm = blockIdx.x * 128, bn = blockIdx.y * 128;
  const int wm = (wave >> 1) * 64, wn = (wave & 1) * 64;
  const int K = 1024;

  f32x4 acc[4][4] = {};
  for (int k0 = 0; k0 < K; k0 += 32){
    #pragma unroll
    for (int c = 0; c < 2; c++){
      int idx = c * 256 + tid;
      int row = idx >> 2, g = (idx & 3) * 8;
      stage16(A + (size_t)(bm + row) * K + k0 + g, &As[idx * 8]);
      stage16(B + (size_t)(bn + row) * K + k0 + g, &Bs[idx * 8]);
    }
    __syncthreads();
    short8 af[4], bf[4];
    #pragma unroll
    for (int i = 0; i < 4; i++) af[i] = *(const short8*)&As[(wm + i*16 + l16)*32 + quad*8];
    #pragma unroll
    for (int j = 0; j < 4; j++) bf[j] = *(const short8*)&Bs[(wn + j*16 + l16)*32 + quad*8];
    #pragma unroll
    for (int i = 0; i < 4; i++)
      #pragma unroll
      for (int j = 0; j < 4; j++)
        acc[i][j] = __builtin_amdgcn_mfma_f32_16x16x32_bf16(af[i], bf[j], acc[i][j], 0, 0, 0);
    __syncthreads();
  }

  if (bn < 2048){
    #pragma unroll
    for (int i = 0; i < 4; i++){
      int mrow = bm + wm + i*16 + quad*4;
      #pragma unroll
      for (int j = 0; j < 4; j++){
        int ncol = bn + wn + j*16 + l16;
        #pragma unroll
        for (int r = 0; r < 4; r++)
          C[(size_t)(mrow + r) * 3072 + ncol] = f2bf(acc[i][j][r]);
      }
    }
  } else {
    // write V transposed: Vg[bh][d][s], 4 s-consecutive bf16 per lane (8B store)
    #pragma unroll
    for (int i = 0; i < 4; i++){
      int srow = bm + wm + i*16 + quad*4;
      int b = srow >> 11, s = srow & 2047;
      #pragma unroll
      for (int j = 0; j < 4; j++){
        int c = bn - 2048 + wn + j*16 + l16;
        int h = c >> 6, d = c & 63;
        ushort4 o;
        o.x = f2bf(acc[i][j][0]); o.y = f2bf(acc[i][j][1]);
        o.z = f2bf(acc[i][j][2]); o.w = f2bf(acc[i][j][3]);
        *(ushort4*)&Vg[((size_t)(b*16 + h)*64 + d) * 2048 + s] = o;
      }
    }
  }
}

// ---------------- gemm2: out = Ob * Wob^T (f32 out), 128x64 tiles, 2 blocks/CU ----
__global__ __launch_bounds__(256) void gemm_out(const unsigned short* __restrict__ A,
                                                const unsigned short* __restrict__ B,
                                                float* __restrict__ Cf)
{
  __shared__ unsigned short As[128*32];
  __shared__ unsigned short Bs[64*32];
  const int tid = threadIdx.x;
  const int wave = tid >> 6, lane = tid & 63, l16 = lane & 15, quad = lane >> 4;
  const int bm = blockIdx.x * 128, bn = blockIdx.y * 64;
  const int wm = (wave >> 1) * 64, wn = (wave & 1) * 32;
  const int K = 1024, N = 1024;

  f32x4 acc[4][2] = {};
  for (int k0 = 0; k0 < K; k0 += 32){
    #pragma unroll
    for (int c = 0; c < 2; c++){
      int idx = c * 256 + tid;
      int row = idx >> 2, g = (idx & 3) * 8;
      stage16(A + (size_t)(bm + row) * K + k0 + g, &As[idx * 8]);
    }
    stage16(B + (size_t)(bn + (tid >> 2)) * K + k0 + (tid & 3) * 8, &Bs[tid * 8]);
    __syncthreads();
    short8 af[4], bf[2];
    #pragma unroll
    for (int i = 0; i < 4; i++) af[i] = *(const short8*)&As[(wm + i*16 + l16)*32 + quad*8];
    #pragma unroll
    for (int j = 0; j < 2; j++) bf[j] = *(const short8*)&Bs[(wn + j*16 + l16)*32 + quad*8];
    #pragma unroll
    for (int i = 0; i < 4; i++)
      #pragma unroll
      for (int j = 0; j < 2; j++)
        acc[i][j] = __builtin_amdgcn_mfma_f32_16x16x32_bf16(af[i], bf[j], acc[i][j], 0, 0, 0);
    __syncthreads();
  }
  #pragma unroll
  for (int i = 0; i < 4; i++){
    int mrow = bm + wm + i*16 + quad*4;
    #pragma unroll
    for (int j = 0; j < 2; j++){
      int ncol = bn + wn + j*16 + l16;
      #pragma unroll
      for (int r = 0; r < 4; r++)
        Cf[(size_t)(mrow + r) * N + ncol] = acc[i][j][r];
    }
  }
}

// ---------------- attention: barrier-free main loop, wave-private operands --------
// Wave w owns keys [w*16, w*16+16) of each 64-key chunk -> K fragment, V^T fragment,
// and mask dwords are wave-private plain global loads (L2-resident via XCD swizzle).
// No LDS, no __syncthreads in the main loop; next chunk's operands register-double-
// buffered so the compiler's vmcnt waits land a full iteration after issue.
__global__ __launch_bounds__(256) void attn(const unsigned short* __restrict__ QKV,
                                            const unsigned short* __restrict__ Vg,
                                            const unsigned char* __restrict__ mask8,
                                            unsigned short* __restrict__ O)
{
  __shared__ char smem[17408];
  float* red   = (float*)smem;             // 16 KB epilogue reduction
  float* lsums = (float*)(smem + 16384);   // 1 KB [wave][q]

  const int tid = threadIdx.x, wave = tid >> 6, lane = tid & 63;
  const int l16 = lane & 15, quad = lane >> 4;
  const int id = blockIdx.x;
  const int xcd = id & 7, m = id >> 3;         // round-robin XCD assumption
  const int bh = xcd * 4 + (m >> 5);           // 4 bh per XCD (K/V stay in this XCD's L2)
  const int qblk = (m & 31) * 64;
  const int b = bh >> 4, h = bh & 15;
  const unsigned short* Qg  = QKV + (size_t)b * 2048 * 3072 + h * 64;
  const unsigned short* Kg  = Qg + 1024;
  const unsigned short* Vgb = Vg + (size_t)bh * 64 * 2048;
  const unsigned char*  mbase = mask8 + (size_t)b * 2048 * 2048;

  // Q B-fragments resident in registers: B[n=q=l16][k=d=ks*32+quad*8+j]
  short8 qf[4][2];
  #pragma unroll
  for (int nt = 0; nt < 4; nt++)
    #pragma unroll
    for (int ks = 0; ks < 2; ks++)
      qf[nt][ks] = *(const short8*)(Qg + (size_t)(qblk + nt*16 + l16) * 3072 + ks*32 + quad*8);

  // per-lane operand pointers (chunk offset advances by 64 keys)
  const unsigned short* kp = Kg + (size_t)(wave*16 + l16) * 3072 + quad*8;           // + ks*32, + j0*3072? NO: keys advance rows
  // careful: K rows are keys -> chunk advances the ROW index. Precompute row pointer:
  // row = j0 + wave*16 + l16 -> ptr = Kg + (j0 + wave*16 + l16)*3072 + quad*8
  const unsigned short* vp = Vgb + (size_t)(l16) * 2048 + wave*16 + quad*4;          // + dt*16*2048, + j0
  const unsigned char*  mp = mbase + (size_t)(qblk + l16) * 2048 + wave*16 + quad*4; // + nt*16*2048, + j0

  f32x4 oacc[4][4] = {};            // [dtile][ntile]: O^T(d=dt*16+quad*4+r, q=nt*16+l16)
  float plsum[4] = {0.f, 0.f, 0.f, 0.f};

  // preload chunk 0 operands
  short8  kf[2];
  short4v vf[4];
  unsigned md[4];
  {
    const unsigned short* kr = kp;   // j0 = 0
    kf[0] = *(const short8*)(kr);
    kf[1] = *(const short8*)(kr + 32);
    #pragma unroll
    for (int dt = 0; dt < 4; dt++) vf[dt] = *(const short4v*)(vp + dt*16*2048);
    #pragma unroll
    for (int nt = 0; nt < 4; nt++) md[nt] = *(const unsigned*)(mp + nt*16*2048);
  }

  for (int c = 0; c < 32; c++){
    const int j0n = (c + 1) * 64;
    // issue next chunk's loads (consumed next iteration -> latency hidden)
    short8  kf_n[2];
    short4v vf_n[4];
    unsigned md_n[4];
    if (c < 31){
      const unsigned short* kr = kp + (size_t)j0n * 3072;
      kf_n[0] = *(const short8*)(kr);
      kf_n[1] = *(const short8*)(kr + 32);
      #pragma unroll
      for (int dt = 0; dt < 4; dt++) vf_n[dt] = *(const short4v*)(vp + dt*16*2048 + j0n);
      #pragma unroll
      for (int nt = 0; nt < 4; nt++) md_n[nt] = *(const unsigned*)(mp + nt*16*2048 + j0n);
    }

    // S^T = K * Q^T : m = wave's 16 keys, n = 64 q (4 tiles), k = d = 64
    short4v b2[4];
    #pragma unroll
    for (int nt = 0; nt < 4; nt++){
      f32x4 a = {0.f, 0.f, 0.f, 0.f};
      a = __builtin_amdgcn_mfma_f32_16x16x32_bf16(kf[0], qf[nt][0], a, 0, 0, 0);
      a = __builtin_amdgcn_mfma_f32_16x16x32_bf16(kf[1], qf[nt][1], a, 0, 0, 0);
      // scores in log2 domain (log2e folded into Wq); masked -> exp2(0)=1
      float p0 = EXP2(a[0] * (float)( md[nt]        & 255u));
      float p1 = EXP2(a[1] * (float)((md[nt] >>  8) & 255u));
      float p2 = EXP2(a[2] * (float)((md[nt] >> 16) & 255u));
      float p3 = EXP2(a[3] * (float)( md[nt] >> 24        ));
      plsum[nt] += (p0 + p1) + (p2 + p3);
      union { unsigned u[2]; short4v s4; } pk;
      pk.u[0] = pack_bf16_rn(p0, p1); pk.u[1] = pack_bf16_rn(p2, p3);
      b2[nt] = pk.s4;
    }

    // O^T += V^T * P^T : A[m=d=l16][k=key=quad*4+j] (regs), B = b2 (regs)
    #pragma unroll
    for (int dt = 0; dt < 4; dt++)
      #pragma unroll
      for (int nt = 0; nt < 4; nt++)
        oacc[dt][nt] = __builtin_amdgcn_mfma_f32_16x16x16bf16_1k(vf[dt], b2[nt], oacc[dt][nt], 0, 0, 0);

    // rotate double-buffered operands
    kf[0] = kf_n[0]; kf[1] = kf_n[1];
    #pragma unroll
    for (int dt = 0; dt < 4; dt++) vf[dt] = vf_n[dt];
    #pragma unroll
    for (int nt = 0; nt < 4; nt++) md[nt] = md_n[nt];
  }

  // ---- epilogue: wave-local lsum reduce, serial cross-wave O reduction ----
  float lw[4];
  #pragma unroll
  for (int nt = 0; nt < 4; nt++){
    float v = plsum[nt];
    v += __shfl_xor(v, 16);
    v += __shfl_xor(v, 32);
    lw[nt] = v;
  }
  __syncthreads();                   // first join of the four waves
  if (quad == 0){
    #pragma unroll
    for (int nt = 0; nt < 4; nt++) lsums[wave*64 + nt*16 + l16] = lw[nt];
  }
  if (wave == 0){
    #pragma unroll
    for (int dt = 0; dt < 4; dt++)
      #pragma unroll
      for (int nt = 0; nt < 4; nt++)
        *(f32x4*)&red[((dt*4 + nt)*64 + lane)*4] = oacc[dt][nt];
  }
  __syncthreads();
  for (int w = 1; w <= 2; w++){
    if (wave == w){
      #pragma unroll
      for (int dt = 0; dt < 4; dt++)
        #pragma unroll
        for (int nt = 0; nt < 4; nt++){
          f32x4* p = (f32x4*)&red[((dt*4 + nt)*64 + lane)*4];
          *p = *p + oacc[dt][nt];
        }
    }
    __syncthreads();
  }
  if (wave == 3){
    float linv[4];
    #pragma unroll
    for (int nt = 0; nt < 4; nt++){
      int q = nt*16 + l16;
      linv[nt] = 1.0f / (lsums[q] + lsums[64 + q] + lsums[128 + q] + lsums[192 + q]);
    }
    #pragma unroll
    for (int dt = 0; dt < 4; dt++)
      #pragma unroll
      for (int nt = 0; nt < 4; nt++){
        f32x4 t = *(f32x4*)&red[((dt*4 + nt)*64 + lane)*4];
        t = t + oacc[dt][nt];
        unsigned u0 = pack_bf16_rn(t[0] * linv[nt], t[1] * linv[nt]);
        unsigned u1 = pack_bf16_rn(t[2] * linv[nt], t[3] * linv[nt]);
        uint2 st; st.x = u0; st.y = u1;
        *(uint2*)&O[(size_t)(b*2048 + qblk + nt*16 + l16) * 1024 + h*64 + dt*16 + quad*4] = st;
      }
  }
}

// ---------------- launch ----------------
extern "C" void kernel_launch(void* const* d_in, const int* in_sizes, int n_in,
                              void* d_out, int out_size, void* d_ws, size_t ws_size,
                              hipStream_t stream)
{
  const float* X  = (const float*)d_in[0];
  const int*   Mk = (const int*)d_in[1];
  const float* Wq = (const float*)d_in[2];
  const float* Wk = (const float*)d_in[3];
  const float* Wv = (const float*)d_in[4];
  const float* Wo = (const float*)d_in[5];
  float* out = (float*)d_out;

  char* ws = (char*)d_ws;
  unsigned short* Xb   = (unsigned short*)(ws + 0);          //  8 MB  [4096][1024]
  unsigned short* Wqkv = (unsigned short*)(ws + 8388608);    //  6 MB  [3072][1024]
  unsigned short* Wob  = (unsigned short*)(ws + 14680064);   //  2 MB  [1024][1024]
  unsigned short* QKV  = (unsigned short*)(ws + 16777216);   // 24 MB  [4096][3072] (V cols unused)
  unsigned short* Ob   = (unsigned short*)(ws + 41943040);   //  8 MB  [4096][1024]
  unsigned char*  M8   = (unsigned char*) (ws + 50331648);   //  8 MB  [2][2048][2048]
  unsigned short* Vg   = (unsigned short*)(ws + 58720256);   //  8 MB  [32][64][2048]

  prep<<<16384, 256, 0, stream>>>(X, Mk, Wq, Wk, Wv, Wo, Xb, Wqkv, Wob, M8);
  gemm_qkv<<<dim3(32, 24), 256, 0, stream>>>(Xb, Wqkv, QKV, Vg);
  attn<<<1024, 256, 0, stream>>>(QKV, Vg, M8, Ob);
  gemm_out<<<dim3(32, 16), 256, 0, stream>>>(Ob, Wob, out);
}

// Round 7
// 264.569 us; speedup vs baseline: 1.1985x; 1.1985x over previous
//
#include <hip/hip_runtime.h>
#include <hip/hip_bf16.h>

using short8  = __attribute__((ext_vector_type(8))) short;
using short4v = __attribute__((ext_vector_type(4))) short;
using f32x4   = __attribute__((ext_vector_type(4))) float;

#if __has_builtin(__builtin_amdgcn_exp2f)
#define EXP2(x) __builtin_amdgcn_exp2f(x)
#else
#define EXP2(x) __expf(0.6931471805599453f*(x))
#endif

__device__ __forceinline__ unsigned short f2bf(float x){
  union { float f; unsigned u; } c; c.f = x;
  unsigned u = c.u + 0x7FFFu + ((c.u >> 16) & 1u);
  return (unsigned short)(u >> 16);
}

__device__ __forceinline__ unsigned pack_bf16_rn(float a, float b){
  __hip_bfloat162 t = __float22bfloat162_rn(make_float2(a, b));
  unsigned u; __builtin_memcpy(&u, &t, 4);
  return u;
}

// ---------------- fused prep: all dtype conversions in one launch ----------------
__global__ __launch_bounds__(256) void prep(const float* __restrict__ X, const int* __restrict__ Mk,
                                            const float* __restrict__ Wq, const float* __restrict__ Wk,
                                            const float* __restrict__ Wv, const float* __restrict__ Wo,
                                            unsigned short* __restrict__ Xb, unsigned short* __restrict__ Wqkv,
                                            unsigned short* __restrict__ Wob, unsigned char* __restrict__ M8)
{
  const int bid = blockIdx.x, tid = threadIdx.x;
  if (bid < 8192){
    const float* src; unsigned short* dst; float scale; int i;
    if (bid < 4096)      { src = X;  dst = Xb;             scale = 1.0f;          i = bid*1024 + tid*4; }
    else if (bid < 5120) { src = Wq; dst = Wqkv;           scale = 0.18033688f;   i = (bid-4096)*1024 + tid*4; } // 1/8 * log2(e)
    else if (bid < 6144) { src = Wk; dst = Wqkv + 1048576; scale = 1.0f;          i = (bid-5120)*1024 + tid*4; }
    else if (bid < 7168) { src = Wv; dst = Wqkv + 2097152; scale = 1.0f;          i = (bid-6144)*1024 + tid*4; }
    else                 { src = Wo; dst = Wob;            scale = 1.0f;          i = (bid-7168)*1024 + tid*4; }
    float4 v = *(const float4*)(src + i);
    ushort4 o;
    o.x = f2bf(v.x * scale); o.y = f2bf(v.y * scale);
    o.z = f2bf(v.z * scale); o.w = f2bf(v.w * scale);
    *(ushort4*)(dst + i) = o;
  } else {
    int i = (bid - 8192)*1024 + tid*4;
    int4 v = *(const int4*)(Mk + i);
    unsigned out = (v.x ? 1u : 0u) | ((v.y ? 1u : 0u) << 8) |
                   ((v.z ? 1u : 0u) << 16) | ((v.w ? 1u : 0u) << 24);
    *(unsigned*)(M8 + i) = out;
  }
}

// ---------------- async global->LDS, width 16 ----------------
__device__ __forceinline__ void stage16(const unsigned short* g, unsigned short* l){
  __builtin_amdgcn_global_load_lds(
      (const __attribute__((address_space(1))) void*)g,
      (__attribute__((address_space(3))) void*)l, 16, 0, 0);
}

// ---------------- gemm1: QKV = Xb * Wqkv^T; V-blocks write Vg transposed ----------
// 1-D grid 768, XCD-swizzled: each XCD owns 3 bn-columns -> its B-tiles (768 KB)
// stay L2-resident across all 32 bm-blocks.
__global__ __launch_bounds__(256) void gemm_qkv(const unsigned short* __restrict__ A,
                                                const unsigned short* __restrict__ B,
                                                unsigned short* __restrict__ C,
                                                unsigned short* __restrict__ Vg)
{
  __shared__ unsigned short As[128*32];
  __shared__ unsigned short Bs[128*32];
  const int tid = threadIdx.x;
  const int wave = tid >> 6, lane = tid & 63, l16 = lane & 15, quad = lane >> 4;
  const int id = blockIdx.x, xcd = id & 7, m = id >> 3;
  const int bm = (m / 3) * 128, bn = (xcd * 3 + (m % 3)) * 128;
  const int wm = (wave >> 1) * 64, wn = (wave & 1) * 64;
  const int K = 1024;

  f32x4 acc[4][4] = {};
  for (int k0 = 0; k0 < K; k0 += 32){
    #pragma unroll
    for (int c = 0; c < 2; c++){
      int idx = c * 256 + tid;
      int row = idx >> 2, g = (idx & 3) * 8;
      stage16(A + (size_t)(bm + row) * K + k0 + g, &As[idx * 8]);
      stage16(B + (size_t)(bn + row) * K + k0 + g, &Bs[idx * 8]);
    }
    __syncthreads();
    short8 af[4], bf[4];
    #pragma unroll
    for (int i = 0; i < 4; i++) af[i] = *(const short8*)&As[(wm + i*16 + l16)*32 + quad*8];
    #pragma unroll
    for (int j = 0; j < 4; j++) bf[j] = *(const short8*)&Bs[(wn + j*16 + l16)*32 + quad*8];
    #pragma unroll
    for (int i = 0; i < 4; i++)
      #pragma unroll
      for (int j = 0; j < 4; j++)
        acc[i][j] = __builtin_amdgcn_mfma_f32_16x16x32_bf16(af[i], bf[j], acc[i][j], 0, 0, 0);
    __syncthreads();
  }

  if (bn < 2048){
    #pragma unroll
    for (int i = 0; i < 4; i++){
      int mrow = bm + wm + i*16 + quad*4;
      #pragma unroll
      for (int j = 0; j < 4; j++){
        int ncol = bn + wn + j*16 + l16;
        #pragma unroll
        for (int r = 0; r < 4; r++)
          C[(size_t)(mrow + r) * 3072 + ncol] = f2bf(acc[i][j][r]);
      }
    }
  } else {
    // write V transposed: Vg[bh][d][s], 4 s-consecutive bf16 per lane (8B store)
    #pragma unroll
    for (int i = 0; i < 4; i++){
      int srow = bm + wm + i*16 + quad*4;
      int b = srow >> 11, s = srow & 2047;
      #pragma unroll
      for (int j = 0; j < 4; j++){
        int c = bn - 2048 + wn + j*16 + l16;
        int h = c >> 6, d = c & 63;
        ushort4 o;
        o.x = f2bf(acc[i][j][0]); o.y = f2bf(acc[i][j][1]);
        o.z = f2bf(acc[i][j][2]); o.w = f2bf(acc[i][j][3]);
        *(ushort4*)&Vg[((size_t)(b*16 + h)*64 + d) * 2048 + s] = o;
      }
    }
  }
}

// ---------------- gemm2: out = Ob * Wob^T (f32 out), 128x64 tiles, XCD-swizzled ----
__global__ __launch_bounds__(256) void gemm_out(const unsigned short* __restrict__ A,
                                                const unsigned short* __restrict__ B,
                                                float* __restrict__ Cf)
{
  __shared__ unsigned short As[128*32];
  __shared__ unsigned short Bs[64*32];
  const int tid = threadIdx.x;
  const int wave = tid >> 6, lane = tid & 63, l16 = lane & 15, quad = lane >> 4;
  const int id = blockIdx.x, xcd = id & 7, m = id >> 3;
  const int bm = (m >> 1) * 128, bn = (xcd * 2 + (m & 1)) * 64;
  const int wm = (wave >> 1) * 64, wn = (wave & 1) * 32;
  const int K = 1024, N = 1024;

  f32x4 acc[4][2] = {};
  for (int k0 = 0; k0 < K; k0 += 32){
    #pragma unroll
    for (int c = 0; c < 2; c++){
      int idx = c * 256 + tid;
      int row = idx >> 2, g = (idx & 3) * 8;
      stage16(A + (size_t)(bm + row) * K + k0 + g, &As[idx * 8]);
    }
    stage16(B + (size_t)(bn + (tid >> 2)) * K + k0 + (tid & 3) * 8, &Bs[tid * 8]);
    __syncthreads();
    short8 af[4], bf[2];
    #pragma unroll
    for (int i = 0; i < 4; i++) af[i] = *(const short8*)&As[(wm + i*16 + l16)*32 + quad*8];
    #pragma unroll
    for (int j = 0; j < 2; j++) bf[j] = *(const short8*)&Bs[(wn + j*16 + l16)*32 + quad*8];
    #pragma unroll
    for (int i = 0; i < 4; i++)
      #pragma unroll
      for (int j = 0; j < 2; j++)
        acc[i][j] = __builtin_amdgcn_mfma_f32_16x16x32_bf16(af[i], bf[j], acc[i][j], 0, 0, 0);
    __syncthreads();
  }
  #pragma unroll
  for (int i = 0; i < 4; i++){
    int mrow = bm + wm + i*16 + quad*4;
    #pragma unroll
    for (int j = 0; j < 2; j++){
      int ncol = bn + wn + j*16 + l16;
      #pragma unroll
      for (int r = 0; r < 4; r++)
        Cf[(size_t)(mrow + r) * N + ncol] = acc[i][j][r];
    }
  }
}

// ---------------- attention: R5 DMA staging + cross-chunk exp/PV pipeline ---------
// Iteration c: barrier (chunk c in LDS), issue DMA(c+1), ds_read kf/vf(c), mask(c),
// issue QK(c) MFMAs, then exp/PV of chunk c-1 from registers (overlaps QK exec).
__global__ __launch_bounds__(256) void attn(const unsigned short* __restrict__ QKV,
                                            const unsigned short* __restrict__ Vg,
                                            const unsigned char* __restrict__ mask8,
                                            unsigned short* __restrict__ O)
{
  __shared__ char smem[33792];
  unsigned short* Ks = (unsigned short*)smem;            // [2][64*64] 16 KB, xor-swizzled 16B blocks
  unsigned short* Vt = (unsigned short*)(smem + 16384);  // [2][64*64] 16 KB, [d][key] xor-swizzled
  float* lsums = (float*)(smem + 32768);                 // 1 KB [wave][q]
  float* red   = (float*)smem;                           // epilogue alias (16 KB over Ks)

  const int tid = threadIdx.x, wave = tid >> 6, lane = tid & 63;
  const int l16 = lane & 15, quad = lane >> 4;
  const int id = blockIdx.x;
  const int xcd = id & 7, m = id >> 3;         // round-robin XCD assumption
  const int bh = xcd * 4 + (m >> 5);           // 4 bh per XCD (K/V stay in this XCD's L2)
  const int qblk = (m & 31) * 64;
  const int b = bh >> 4, h = bh & 15;
  const unsigned short* Qg  = QKV + (size_t)b * 2048 * 3072 + h * 64;
  const unsigned short* Kg  = Qg + 1024;
  const unsigned short* Vgb = Vg + (size_t)bh * 64 * 2048;
  const unsigned char*  mbase = mask8 + (size_t)b * 2048 * 2048;

  // Q B-fragments resident in registers: B[n=q=l16][k=d=ks*32+quad*8+j]
  short8 qf[4][2];
  #pragma unroll
  for (int nt = 0; nt < 4; nt++)
    #pragma unroll
    for (int ks = 0; ks < 2; ks++)
      qf[nt][ks] = *(const short8*)(Qg + (size_t)(qblk + nt*16 + l16) * 3072 + ks*32 + quad*8);

  f32x4 oacc[4][4] = {};            // [dtile][ntile]: O^T(d=dt*16+quad*4+r, q=nt*16+l16)
  float plsum[4] = {0.f, 0.f, 0.f, 0.f};
  const int sw = l16 & 7;

  // prologue: stage chunk 0 into buffer 0
  #pragma unroll
  for (int it = 0; it < 2; it++){
    int s = it * 256 + tid;
    int row = s >> 3, bg = (s & 7) ^ (row & 7);
    stage16(Kg + (size_t)row * 3072 + bg * 8, Ks + s * 8);
    stage16(Vgb + (size_t)row * 2048 + bg * 8, Vt + s * 8);
  }

  // pipeline state (chunk c-1 operands, in registers)
  f32x4   sacc_p[4];
  short4v vf_p[4];
  unsigned md_p[4];

  for (int c = 0; c < 32; c++){
    const int j0 = c * 64;
    const int buf = (c & 1) * 4096;
    __syncthreads();   // chunk-c DMAs landed; also drains last iter's ds_reads

    // issue next chunk's DMAs into the other buffer
    if (c < 31){
      const int nj = j0 + 64, nbuf = ((c + 1) & 1) * 4096;
      #pragma unroll
      for (int it = 0; it < 2; it++){
        int s = it * 256 + tid;
        int row = s >> 3, bg = (s & 7) ^ (row & 7);
        stage16(Kg + (size_t)(nj + row) * 3072 + bg * 8, Ks + nbuf + s * 8);
        stage16(Vgb + (size_t)row * 2048 + nj + bg * 8, Vt + nbuf + s * 8);
      }
    }

    // chunk-c operands: K fragments, V^T fragments (regs, used next iter), mask
    short8 kf0 = *(const short8*)&Ks[buf + (wave*16 + l16) * 64 + ((0 + quad) ^ sw) * 8];
    short8 kf1 = *(const short8*)&Ks[buf + (wave*16 + l16) * 64 + ((4 + quad) ^ sw) * 8];
    short4v vf_c[4];
    #pragma unroll
    for (int dt = 0; dt < 4; dt++){
      int physb = (wave*2 + (quad >> 1)) ^ sw;
      vf_c[dt] = *(const short4v*)&Vt[buf + (dt*16 + l16) * 64 + physb * 8 + (quad & 1) * 4];
    }
    unsigned md_c[4];
    #pragma unroll
    for (int nt = 0; nt < 4; nt++)
      md_c[nt] = *(const unsigned*)(mbase + (size_t)(qblk + nt*16 + l16) * 2048 + j0 + wave*16 + quad*4);

    // QK(c): S^T = K * Q^T ; results consumed NEXT iteration
    f32x4 sacc_c[4];
    #pragma unroll
    for (int nt = 0; nt < 4; nt++){
      f32x4 a = {0.f, 0.f, 0.f, 0.f};
      a = __builtin_amdgcn_mfma_f32_16x16x32_bf16(kf0, qf[nt][0], a, 0, 0, 0);
      a = __builtin_amdgcn_mfma_f32_16x16x32_bf16(kf1, qf[nt][1], a, 0, 0, 0);
      sacc_c[nt] = a;
    }

    // exp/PV for chunk c-1 (register operands only; overlaps QK(c) execution)
    if (c > 0){
      short4v b2[4];
      #pragma unroll
      for (int nt = 0; nt < 4; nt++){
        float p0 = EXP2(sacc_p[nt][0] * (float)( md_p[nt]        & 255u));
        float p1 = EXP2(sacc_p[nt][1] * (float)((md_p[nt] >>  8) & 255u));
        float p2 = EXP2(sacc_p[nt][2] * (float)((md_p[nt] >> 16) & 255u));
        float p3 = EXP2(sacc_p[nt][3] * (float)( md_p[nt] >> 24        ));
        plsum[nt] += (p0 + p1) + (p2 + p3);
        union { unsigned u[2]; short4v s4; } pk;
        pk.u[0] = pack_bf16_rn(p0, p1); pk.u[1] = pack_bf16_rn(p2, p3);
        b2[nt] = pk.s4;
      }
      #pragma unroll
      for (int dt = 0; dt < 4; dt++)
        #pragma unroll
        for (int nt = 0; nt < 4; nt++)
          oacc[dt][nt] = __builtin_amdgcn_mfma_f32_16x16x16bf16_1k(vf_p[dt], b2[nt], oacc[dt][nt], 0, 0, 0);
    }

    // rotate pipeline registers
    #pragma unroll
    for (int nt = 0; nt < 4; nt++){ sacc_p[nt] = sacc_c[nt]; md_p[nt] = md_c[nt]; }
    #pragma unroll
    for (int dt = 0; dt < 4; dt++) vf_p[dt] = vf_c[dt];
  }

  // drain pipeline: exp/PV for chunk 31
  {
    short4v b2[4];
    #pragma unroll
    for (int nt = 0; nt < 4; nt++){
      float p0 = EXP2(sacc_p[nt][0] * (float)( md_p[nt]        & 255u));
      float p1 = EXP2(sacc_p[nt][1] * (float)((md_p[nt] >>  8) & 255u));
      float p2 = EXP2(sacc_p[nt][2] * (float)((md_p[nt] >> 16) & 255u));
      float p3 = EXP2(sacc_p[nt][3] * (float)( md_p[nt] >> 24        ));
      plsum[nt] += (p0 + p1) + (p2 + p3);
      union { unsigned u[2]; short4v s4; } pk;
      pk.u[0] = pack_bf16_rn(p0, p1); pk.u[1] = pack_bf16_rn(p2, p3);
      b2[nt] = pk.s4;
    }
    #pragma unroll
    for (int dt = 0; dt < 4; dt++)
      #pragma unroll
      for (int nt = 0; nt < 4; nt++)
        oacc[dt][nt] = __builtin_amdgcn_mfma_f32_16x16x16bf16_1k(vf_p[dt], b2[nt], oacc[dt][nt], 0, 0, 0);
  }

  // ---- epilogue: wave-local lsum reduce, serial cross-wave O reduction ----
  float lw[4];
  #pragma unroll
  for (int nt = 0; nt < 4; nt++){
    float v = plsum[nt];
    v += __shfl_xor(v, 16);
    v += __shfl_xor(v, 32);
    lw[nt] = v;
  }
  __syncthreads();                   // all chunk LDS reads done; safe to alias red/lsums
  if (quad == 0){
    #pragma unroll
    for (int nt = 0; nt < 4; nt++) lsums[wave*64 + nt*16 + l16] = lw[nt];
  }
  if (wave == 0){
    #pragma unroll
    for (int dt = 0; dt < 4; dt++)
      #pragma unroll
      for (int nt = 0; nt < 4; nt++)
        *(f32x4*)&red[((dt*4 + nt)*64 + lane)*4] = oacc[dt][nt];
  }
  __syncthreads();
  for (int w = 1; w <= 2; w++){
    if (wave == w){
      #pragma unroll
      for (int dt = 0; dt < 4; dt++)
        #pragma unroll
        for (int nt = 0; nt < 4; nt++){
          f32x4* p = (f32x4*)&red[((dt*4 + nt)*64 + lane)*4];
          *p = *p + oacc[dt][nt];
        }
    }
    __syncthreads();
  }
  if (wave == 3){
    float linv[4];
    #pragma unroll
    for (int nt = 0; nt < 4; nt++){
      int q = nt*16 + l16;
      linv[nt] = 1.0f / (lsums[q] + lsums[64 + q] + lsums[128 + q] + lsums[192 + q]);
    }
    #pragma unroll
    for (int dt = 0; dt < 4; dt++)
      #pragma unroll
      for (int nt = 0; nt < 4; nt++){
        f32x4 t = *(f32x4*)&red[((dt*4 + nt)*64 + lane)*4];
        t = t + oacc[dt][nt];
        unsigned u0 = pack_bf16_rn(t[0] * linv[nt], t[1] * linv[nt]);
        unsigned u1 = pack_bf16_rn(t[2] * linv[nt], t[3] * linv[nt]);
        uint2 st; st.x = u0; st.y = u1;
        *(uint2*)&O[(size_t)(b*2048 + qblk + nt*16 + l16) * 1024 + h*64 + dt*16 + quad*4] = st;
      }
  }
}

// ---------------- launch ----------------
extern "C" void kernel_launch(void* const* d_in, const int* in_sizes, int n_in,
                              void* d_out, int out_size, void* d_ws, size_t ws_size,
                              hipStream_t stream)
{
  const float* X  = (const float*)d_in[0];
  const int*   Mk = (const int*)d_in[1];
  const float* Wq = (const float*)d_in[2];
  const float* Wk = (const float*)d_in[3];
  const float* Wv = (const float*)d_in[4];
  const float* Wo = (const float*)d_in[5];
  float* out = (float*)d_out;

  char* ws = (char*)d_ws;
  unsigned short* Xb   = (unsigned short*)(ws + 0);          //  8 MB  [4096][1024]
  unsigned short* Wqkv = (unsigned short*)(ws + 8388608);    //  6 MB  [3072][1024]
  unsigned short* Wob  = (unsigned short*)(ws + 14680064);   //  2 MB  [1024][1024]
  unsigned short* QKV  = (unsigned short*)(ws + 16777216);   // 24 MB  [4096][3072] (V cols unused)
  unsigned short* Ob   = (unsigned short*)(ws + 41943040);   //  8 MB  [4096][1024]
  unsigned char*  M8   = (unsigned char*) (ws + 50331648);   //  8 MB  [2][2048][2048]
  unsigned short* Vg   = (unsigned short*)(ws + 58720256);   //  8 MB  [32][64][2048]

  prep<<<16384, 256, 0, stream>>>(X, Mk, Wq, Wk, Wv, Wo, Xb, Wqkv, Wob, M8);
  gemm_qkv<<<768, 256, 0, stream>>>(Xb, Wqkv, QKV, Vg);
  attn<<<1024, 256, 0, stream>>>(QKV, Vg, M8, Ob);
  gemm_out<<<512, 256, 0, stream>>>(Ob, Wob, out);
}

// Round 8
// 258.873 us; speedup vs baseline: 1.2249x; 1.0220x over previous
//
#include <hip/hip_runtime.h>
#include <hip/hip_bf16.h>

using short8  = __attribute__((ext_vector_type(8))) short;
using short4v = __attribute__((ext_vector_type(4))) short;
using f32x4   = __attribute__((ext_vector_type(4))) float;

#if __has_builtin(__builtin_amdgcn_exp2f)
#define EXP2(x) __builtin_amdgcn_exp2f(x)
#else
#define EXP2(x) __expf(0.6931471805599453f*(x))
#endif

__device__ __forceinline__ unsigned short f2bf(float x){
  union { float f; unsigned u; } c; c.f = x;
  unsigned u = c.u + 0x7FFFu + ((c.u >> 16) & 1u);
  return (unsigned short)(u >> 16);
}

__device__ __forceinline__ unsigned pack_bf16_rn(float a, float b){
  __hip_bfloat162 t = __float22bfloat162_rn(make_float2(a, b));
  unsigned u; __builtin_memcpy(&u, &t, 4);
  return u;
}

// ---------------- fused prep: all dtype conversions in one launch ----------------
__global__ __launch_bounds__(256) void prep(const float* __restrict__ X, const int* __restrict__ Mk,
                                            const float* __restrict__ Wq, const float* __restrict__ Wk,
                                            const float* __restrict__ Wv, const float* __restrict__ Wo,
                                            unsigned short* __restrict__ Xb, unsigned short* __restrict__ Wqkv,
                                            unsigned short* __restrict__ Wob, unsigned char* __restrict__ M8)
{
  const int bid = blockIdx.x, tid = threadIdx.x;
  if (bid < 8192){
    const float* src; unsigned short* dst; float scale; int i;
    if (bid < 4096)      { src = X;  dst = Xb;             scale = 1.0f;          i = bid*1024 + tid*4; }
    else if (bid < 5120) { src = Wq; dst = Wqkv;           scale = 0.18033688f;   i = (bid-4096)*1024 + tid*4; } // 1/8 * log2(e)
    else if (bid < 6144) { src = Wk; dst = Wqkv + 1048576; scale = 1.0f;          i = (bid-5120)*1024 + tid*4; }
    else if (bid < 7168) { src = Wv; dst = Wqkv + 2097152; scale = 1.0f;          i = (bid-6144)*1024 + tid*4; }
    else                 { src = Wo; dst = Wob;            scale = 1.0f;          i = (bid-7168)*1024 + tid*4; }
    float4 v = *(const float4*)(src + i);
    ushort4 o;
    o.x = f2bf(v.x * scale); o.y = f2bf(v.y * scale);
    o.z = f2bf(v.z * scale); o.w = f2bf(v.w * scale);
    *(ushort4*)(dst + i) = o;
  } else {
    int i = (bid - 8192)*1024 + tid*4;
    int4 v = *(const int4*)(Mk + i);
    unsigned out = (v.x ? 1u : 0u) | ((v.y ? 1u : 0u) << 8) |
                   ((v.z ? 1u : 0u) << 16) | ((v.w ? 1u : 0u) << 24);
    *(unsigned*)(M8 + i) = out;
  }
}

// ---------------- async global->LDS, width 16 ----------------
__device__ __forceinline__ void stage16(const unsigned short* g, unsigned short* l){
  __builtin_amdgcn_global_load_lds(
      (const __attribute__((address_space(1))) void*)g,
      (__attribute__((address_space(3))) void*)l, 16, 0, 0);
}

// ---------------- gemm1: QKV = Xb * Wqkv^T; V-blocks write Vg transposed ----------
__global__ __launch_bounds__(256) void gemm_qkv(const unsigned short* __restrict__ A,
                                                const unsigned short* __restrict__ B,
                                                unsigned short* __restrict__ C,
                                                unsigned short* __restrict__ Vg)
{
  __shared__ unsigned short As[128*32];
  __shared__ unsigned short Bs[128*32];
  const int tid = threadIdx.x;
  const int wave = tid >> 6, lane = tid & 63, l16 = lane & 15, quad = lane >> 4;
  const int id = blockIdx.x, xcd = id & 7, m = id >> 3;
  const int bm = (m / 3) * 128, bn = (xcd * 3 + (m % 3)) * 128;
  const int wm = (wave >> 1) * 64, wn = (wave & 1) * 64;
  const int K = 1024;

  f32x4 acc[4][4] = {};
  for (int k0 = 0; k0 < K; k0 += 32){
    #pragma unroll
    for (int c = 0; c < 2; c++){
      int idx = c * 256 + tid;
      int row = idx >> 2, g = (idx & 3) * 8;
      stage16(A + (size_t)(bm + row) * K + k0 + g, &As[idx * 8]);
      stage16(B + (size_t)(bn + row) * K + k0 + g, &Bs[idx * 8]);
    }
    __syncthreads();
    short8 af[4], bf[4];
    #pragma unroll
    for (int i = 0; i < 4; i++) af[i] = *(const short8*)&As[(wm + i*16 + l16)*32 + quad*8];
    #pragma unroll
    for (int j = 0; j < 4; j++) bf[j] = *(const short8*)&Bs[(wn + j*16 + l16)*32 + quad*8];
    #pragma unroll
    for (int i = 0; i < 4; i++)
      #pragma unroll
      for (int j = 0; j < 4; j++)
        acc[i][j] = __builtin_amdgcn_mfma_f32_16x16x32_bf16(af[i], bf[j], acc[i][j], 0, 0, 0);
    __syncthreads();
  }

  if (bn < 2048){
    #pragma unroll
    for (int i = 0; i < 4; i++){
      int mrow = bm + wm + i*16 + quad*4;
      #pragma unroll
      for (int j = 0; j < 4; j++){
        int ncol = bn + wn + j*16 + l16;
        #pragma unroll
        for (int r = 0; r < 4; r++)
          C[(size_t)(mrow + r) * 3072 + ncol] = f2bf(acc[i][j][r]);
      }
    }
  } else {
    // write V transposed: Vg[bh][d][s], 4 s-consecutive bf16 per lane (8B store)
    #pragma unroll
    for (int i = 0; i < 4; i++){
      int srow = bm + wm + i*16 + quad*4;
      int b = srow >> 11, s = srow & 2047;
      #pragma unroll
      for (int j = 0; j < 4; j++){
        int c = bn - 2048 + wn + j*16 + l16;
        int h = c >> 6, d = c & 63;
        ushort4 o;
        o.x = f2bf(acc[i][j][0]); o.y = f2bf(acc[i][j][1]);
        o.z = f2bf(acc[i][j][2]); o.w = f2bf(acc[i][j][3]);
        *(ushort4*)&Vg[((size_t)(b*16 + h)*64 + d) * 2048 + s] = o;
      }
    }
  }
}

// ---------------- gemm2: out = Ob * Wob^T (f32 out), 128x64 tiles, XCD-swizzled ----
__global__ __launch_bounds__(256) void gemm_out(const unsigned short* __restrict__ A,
                                                const unsigned short* __restrict__ B,
                                                float* __restrict__ Cf)
{
  __shared__ unsigned short As[128*32];
  __shared__ unsigned short Bs[64*32];
  const int tid = threadIdx.x;
  const int wave = tid >> 6, lane = tid & 63, l16 = lane & 15, quad = lane >> 4;
  const int id = blockIdx.x, xcd = id & 7, m = id >> 3;
  const int bm = (m >> 1) * 128, bn = (xcd * 2 + (m & 1)) * 64;
  const int wm = (wave >> 1) * 64, wn = (wave & 1) * 32;
  const int K = 1024, N = 1024;

  f32x4 acc[4][2] = {};
  for (int k0 = 0; k0 < K; k0 += 32){
    #pragma unroll
    for (int c = 0; c < 2; c++){
      int idx = c * 256 + tid;
      int row = idx >> 2, g = (idx & 3) * 8;
      stage16(A + (size_t)(bm + row) * K + k0 + g, &As[idx * 8]);
    }
    stage16(B + (size_t)(bn + (tid >> 2)) * K + k0 + (tid & 3) * 8, &Bs[tid * 8]);
    __syncthreads();
    short8 af[4], bf[2];
    #pragma unroll
    for (int i = 0; i < 4; i++) af[i] = *(const short8*)&As[(wm + i*16 + l16)*32 + quad*8];
    #pragma unroll
    for (int j = 0; j < 2; j++) bf[j] = *(const short8*)&Bs[(wn + j*16 + l16)*32 + quad*8];
    #pragma unroll
    for (int i = 0; i < 4; i++)
      #pragma unroll
      for (int j = 0; j < 2; j++)
        acc[i][j] = __builtin_amdgcn_mfma_f32_16x16x32_bf16(af[i], bf[j], acc[i][j], 0, 0, 0);
    __syncthreads();
  }
  #pragma unroll
  for (int i = 0; i < 4; i++){
    int mrow = bm + wm + i*16 + quad*4;
    #pragma unroll
    for (int j = 0; j < 2; j++){
      int ncol = bn + wn + j*16 + l16;
      #pragma unroll
      for (int r = 0; r < 4; r++)
        Cf[(size_t)(mrow + r) * N + ncol] = acc[i][j][r];
    }
  }
}

// ---------------- attention: LDS-P, disjoint d-strips, small accumulators ---------
// Wave w: computes S^T strip (its 16 keys x 64 q), exp+packs, writes P^T to LDS;
// then owns O^T d-strip [w*16, w*16+16) over ALL 64 keys of the chunk.
// oacc = 16 AGPRs (was 64) -> 3 waves/SIMD instead of 2. Barrier B is a raw
// s_barrier + lgkmcnt(0)-only wait so in-flight K/V DMAs (vmcnt) are NOT drained.
__global__ __launch_bounds__(256, 3) void attn(const unsigned short* __restrict__ QKV,
                                               const unsigned short* __restrict__ Vg,
                                               const unsigned char* __restrict__ mask8,
                                               unsigned short* __restrict__ O)
{
  __shared__ char smem[40960];
  unsigned short* Ks = (unsigned short*)smem;            // [2][64*64] 16 KB, xor-swizzled 16B blocks
  unsigned short* Vt = (unsigned short*)(smem + 16384);  // [2][64*64] 16 KB, [d][key] xor-swizzled
  unsigned short* Ps = (unsigned short*)(smem + 32768);  //  8 KB [q][key] bf16, xor-swizzled
  float* lsums = (float*)smem;                           // epilogue alias over dead Ks: [q][4] f32

  const int tid = threadIdx.x, wave = tid >> 6, lane = tid & 63;
  const int l16 = lane & 15, quad = lane >> 4;
  const int id = blockIdx.x;
  const int xcd = id & 7, m = id >> 3;         // round-robin XCD assumption
  const int bh = xcd * 4 + (m >> 5);           // 4 bh per XCD (K/V stay in this XCD's L2)
  const int qblk = (m & 31) * 64;
  const int b = bh >> 4, h = bh & 15;
  const unsigned short* Qg  = QKV + (size_t)b * 2048 * 3072 + h * 64;
  const unsigned short* Kg  = Qg + 1024;
  const unsigned short* Vgb = Vg + (size_t)bh * 64 * 2048;
  const unsigned char*  mbase = mask8 + (size_t)b * 2048 * 2048;

  // Q B-fragments resident in registers: B[n=q=l16][k=d=ks*32+quad*8+j]
  short8 qf[4][2];
  #pragma unroll
  for (int nt = 0; nt < 4; nt++)
    #pragma unroll
    for (int ks = 0; ks < 2; ks++)
      qf[nt][ks] = *(const short8*)(Qg + (size_t)(qblk + nt*16 + l16) * 3072 + ks*32 + quad*8);

  f32x4 oacc[4] = {};               // O^T strip: d = wave*16+quad*4+r, q = nt*16+l16
  float plsum[4] = {0.f, 0.f, 0.f, 0.f};
  const int sw = l16 & 7;

  // prologue: stage chunk 0 into buffer 0
  #pragma unroll
  for (int it = 0; it < 2; it++){
    int s = it * 256 + tid;
    int row = s >> 3, bg = (s & 7) ^ (row & 7);
    stage16(Kg + (size_t)row * 3072 + bg * 8, Ks + s * 8);
    stage16(Vgb + (size_t)row * 2048 + bg * 8, Vt + s * 8);
  }

  for (int c = 0; c < 32; c++){
    const int j0 = c * 64;
    const int buf = (c & 1) * 4096;
    __syncthreads();   // A: chunk-c DMAs landed (vmcnt), prev PV's Ps reads done (lgkm)

    // issue next chunk's DMAs; they fly through QK+exp+P-write+PV, drained at next A
    if (c < 31){
      const int nj = j0 + 64, nbuf = ((c + 1) & 1) * 4096;
      #pragma unroll
      for (int it = 0; it < 2; it++){
        int s = it * 256 + tid;
        int row = s >> 3, bg = (s & 7) ^ (row & 7);
        stage16(Kg + (size_t)(nj + row) * 3072 + bg * 8, Ks + nbuf + s * 8);
        stage16(Vgb + (size_t)row * 2048 + nj + bg * 8, Vt + nbuf + s * 8);
      }
    }

    // mask dwords for this wave's 16 keys (4 consecutive keys per lane)
    unsigned md[4];
    #pragma unroll
    for (int nt = 0; nt < 4; nt++)
      md[nt] = *(const unsigned*)(mbase + (size_t)(qblk + nt*16 + l16) * 2048 + j0 + wave*16 + quad*4);

    // S^T = K * Q^T for this wave's 16 keys; exp; pack; write P^T strip to LDS
    short8 kf0 = *(const short8*)&Ks[buf + (wave*16 + l16) * 64 + ((0 + quad) ^ sw) * 8];
    short8 kf1 = *(const short8*)&Ks[buf + (wave*16 + l16) * 64 + ((4 + quad) ^ sw) * 8];
    #pragma unroll
    for (int nt = 0; nt < 4; nt++){
      f32x4 a = {0.f, 0.f, 0.f, 0.f};
      a = __builtin_amdgcn_mfma_f32_16x16x32_bf16(kf0, qf[nt][0], a, 0, 0, 0);
      a = __builtin_amdgcn_mfma_f32_16x16x32_bf16(kf1, qf[nt][1], a, 0, 0, 0);
      // scores in log2 domain (log2e folded into Wq); masked -> exp2(0)=1
      float p0 = EXP2(a[0] * (float)( md[nt]        & 255u));
      float p1 = EXP2(a[1] * (float)((md[nt] >>  8) & 255u));
      float p2 = EXP2(a[2] * (float)((md[nt] >> 16) & 255u));
      float p3 = EXP2(a[3] * (float)( md[nt] >> 24        ));
      plsum[nt] += (p0 + p1) + (p2 + p3);
      uint2 st; st.x = pack_bf16_rn(p0, p1); st.y = pack_bf16_rn(p2, p3);
      // Ps[q = nt*16+l16][keys wave*16+quad*4 .. +3], xor-swizzled 16B blocks
      *(uint2*)&Ps[(nt*16 + l16) * 64 + ((wave*2 + (quad >> 1)) ^ sw) * 8 + (quad & 1) * 4] = st;
    }

    // B: P^T ready. LDS-only wait + raw barrier (does NOT drain the c+1 DMAs).
    __asm__ volatile("s_waitcnt lgkmcnt(0)" ::: "memory");
    __builtin_amdgcn_s_barrier();
    __asm__ volatile("" ::: "memory");

    // O^T strip += V^T * P^T over all 64 keys (4 k-steps of 16)
    #pragma unroll
    for (int kk = 0; kk < 4; kk++){
      int pb = (kk*2 + (quad >> 1)) ^ sw;
      short4v a2 = *(const short4v*)&Vt[buf + (wave*16 + l16) * 64 + pb * 8 + (quad & 1) * 4];
      #pragma unroll
      for (int nt = 0; nt < 4; nt++){
        short4v b2 = *(const short4v*)&Ps[(nt*16 + l16) * 64 + pb * 8 + (quad & 1) * 4];
        oacc[nt] = __builtin_amdgcn_mfma_f32_16x16x16bf16_1k(a2, b2, oacc[nt], 0, 0, 0);
      }
    }
  }

  // ---- epilogue: lsum cross-wave reduce via LDS; disjoint O store (no O reduce) ----
  float lw[4];
  #pragma unroll
  for (int nt = 0; nt < 4; nt++){
    float v = plsum[nt];
    v += __shfl_xor(v, 16);
    v += __shfl_xor(v, 32);
    lw[nt] = v;
  }
  __syncthreads();                   // PV ds_reads done; Ks dead -> lsums alias safe
  if (quad == 0){
    #pragma unroll
    for (int nt = 0; nt < 4; nt++) lsums[(nt*16 + l16) * 4 + wave] = lw[nt];
  }
  __syncthreads();
  float linv[4];
  #pragma unroll
  for (int nt = 0; nt < 4; nt++){
    f32x4 ls = *(const f32x4*)&lsums[(nt*16 + l16) * 4];
    linv[nt] = 1.0f / (ls[0] + ls[1] + ls[2] + ls[3]);
  }
  #pragma unroll
  for (int nt = 0; nt < 4; nt++){
    f32x4 t = oacc[nt];
    unsigned u0 = pack_bf16_rn(t[0] * linv[nt], t[1] * linv[nt]);
    unsigned u1 = pack_bf16_rn(t[2] * linv[nt], t[3] * linv[nt]);
    uint2 st; st.x = u0; st.y = u1;
    *(uint2*)&O[(size_t)(b*2048 + qblk + nt*16 + l16) * 1024 + h*64 + wave*16 + quad*4] = st;
  }
}

// ---------------- launch ----------------
extern "C" void kernel_launch(void* const* d_in, const int* in_sizes, int n_in,
                              void* d_out, int out_size, void* d_ws, size_t ws_size,
                              hipStream_t stream)
{
  const float* X  = (const float*)d_in[0];
  const int*   Mk = (const int*)d_in[1];
  const float* Wq = (const float*)d_in[2];
  const float* Wk = (const float*)d_in[3];
  const float* Wv = (const float*)d_in[4];
  const float* Wo = (const float*)d_in[5];
  float* out = (float*)d_out;

  char* ws = (char*)d_ws;
  unsigned short* Xb   = (unsigned short*)(ws + 0);          //  8 MB  [4096][1024]
  unsigned short* Wqkv = (unsigned short*)(ws + 8388608);    //  6 MB  [3072][1024]
  unsigned short* Wob  = (unsigned short*)(ws + 14680064);   //  2 MB  [1024][1024]
  unsigned short* QKV  = (unsigned short*)(ws + 16777216);   // 24 MB  [4096][3072] (V cols unused)
  unsigned short* Ob   = (unsigned short*)(ws + 41943040);   //  8 MB  [4096][1024]
  unsigned char*  M8   = (unsigned char*) (ws + 50331648);   //  8 MB  [2][2048][2048]
  unsigned short* Vg   = (unsigned short*)(ws + 58720256);   //  8 MB  [32][64][2048]

  prep<<<16384, 256, 0, stream>>>(X, Mk, Wq, Wk, Wv, Wo, Xb, Wqkv, Wob, M8);
  gemm_qkv<<<768, 256, 0, stream>>>(Xb, Wqkv, QKV, Vg);
  attn<<<1024, 256, 0, stream>>>(QKV, Vg, M8, Ob);
  gemm_out<<<512, 256, 0, stream>>>(Ob, Wob, out);
}